// Round 1
// baseline (962.722 us; speedup 1.0000x reference)
//
#include <hip/hip_runtime.h>

#define N_STFT 1025
#define N_MELS 128
#define BATCH 4
#define TIME 1024
#define MAX_ITER 20

// Extract per-frequency sparse filterbank structure: each fb row f has at most
// 2 nonzeros at adjacent mel indices (m0, m0+1) — triangular filters.
__global__ void imel_prep(const float* __restrict__ fb, int* __restrict__ m0f,
                          float* __restrict__ w0a, float* __restrict__ w1a) {
  int f = blockIdx.x * blockDim.x + threadIdx.x;
  if (f >= N_STFT) return;
  const float* row = fb + (size_t)f * N_MELS;
  int m0 = -1;
  for (int m = 0; m < N_MELS; ++m) {
    if (row[m] != 0.0f) { m0 = m; break; }
  }
  if (m0 < 0) m0 = 0;                      // all-zero row (f=0): weights 0
  if (m0 > N_MELS - 2) m0 = N_MELS - 2;    // keep m0+1 in range
  m0f[f] = m0;
  w0a[f] = row[m0];
  w1a[f] = row[m0 + 1];
}

// One wave per (b,t) row; 4 waves (4 consecutive t) per workgroup.
// spec/buf/weights in registers; per-wave s_P / s_diff in LDS.
__global__ __launch_bounds__(256, 4) void imel_main(
    const float* __restrict__ melspec, const float* __restrict__ spec_init,
    const int* __restrict__ m0f, const float* __restrict__ w0a,
    const float* __restrict__ w1a, float* __restrict__ out) {
  __shared__ float s_P[4][N_MELS];
  __shared__ float s_diff[4][N_MELS];
  __shared__ float s_out[4][1060];   // swizzle-padded: idx = f + (f>>5), max 1056

  const int tid = threadIdx.x;
  const int w = tid >> 6;       // wave = local row
  const int l = tid & 63;
  const int blk = blockIdx.x;
  const int b = blk >> 8;
  const int t0 = (blk & 255) << 2;
  const int t = t0 + w;

  // lane owns contiguous chunk f in [16*l, 16*l+16); lane 63 also owns f=1024
  float rs[17], rb[17], rw0[17], rw1[17];
  int rm0[17];

  const float* srow = spec_init + ((size_t)(b * TIME + t)) * N_STFT;
#pragma unroll
  for (int k = 0; k < 17; ++k) {
    const int f = (l << 4) + k;
    const bool ok = (k < 16) || (l == 63);
    if (ok) {
      rs[k] = srow[f];
      rm0[k] = m0f[f];
      rw0[k] = w0a[f];
      rw1[k] = w1a[f];
    } else {
      rs[k] = 0.f; rm0[k] = 0; rw0[k] = 0.f; rw1[k] = 0.f;
    }
    rb[k] = 0.f;
  }

  // mel targets for the diff phase: lane handles mels l and l+64
  const float melA = melspec[((size_t)b * N_MELS + l) * TIME + t];
  const float melB = melspec[((size_t)b * N_MELS + l + 64) * TIME + t];

  s_P[w][l] = 0.f;
  s_P[w][l + 64] = 0.f;
  __syncthreads();

  const float NEG_INV = -2.0f / (BATCH * TIME);  // grad prefactor (negated)
  for (int it = 0; it < MAX_ITER; ++it) {
    // ---- forward: P[m] += spec[f] * fb[f,m], 2-term scatter per f ----
#pragma unroll
    for (int k = 0; k < 17; ++k) {
      if (k < 16 || l == 63) {
        atomicAdd(&s_P[w][rm0[k]], rs[k] * rw0[k]);
        atomicAdd(&s_P[w][rm0[k] + 1], rs[k] * rw1[k]);
      }
    }
    __syncthreads();
    // ---- diff = mel - P; reset P for next iteration ----
    s_diff[w][l] = melA - s_P[w][l];
    s_diff[w][l + 64] = melB - s_P[w][l + 64];
    s_P[w][l] = 0.f;
    s_P[w][l + 64] = 0.f;
    __syncthreads();
    // ---- backward + momentum update + clamp ----
#pragma unroll
    for (int k = 0; k < 17; ++k) {
      if (k < 16 || l == 63) {
        const float d0 = s_diff[w][rm0[k]];
        const float d1 = s_diff[w][rm0[k] + 1];
        const float g = NEG_INV * (d0 * rw0[k] + d1 * rw1[k]);
        rb[k] = 0.9f * rb[k] + g;
        const float s = rs[k] - 0.3f * rb[k];
        rs[k] = s > 0.f ? s : 0.f;
      }
    }
    // no barrier needed: s_P/s_diff are wave-private; next barrier orders rest
  }

  // ---- epilogue: transpose (row-major in regs) -> (B, F, T) via LDS ----
#pragma unroll
  for (int k = 0; k < 17; ++k) {
    if (k < 16 || l == 63) {
      const int f = (l << 4) + k;
      s_out[w][f + (f >> 5)] = rs[k];
    }
  }
  __syncthreads();

  const int tl = tid & 3;   // t offset within the WG's 4 rows
  const int fg = tid >> 2;  // 64 f phases
  float* obase = out + ((size_t)b * N_STFT) * TIME + t0 + tl;
  for (int f = fg; f < N_STFT; f += 64) {
    obase[(size_t)f * TIME] = s_out[tl][f + (f >> 5)];
  }
}

extern "C" void kernel_launch(void* const* d_in, const int* in_sizes, int n_in,
                              void* d_out, int out_size, void* d_ws, size_t ws_size,
                              hipStream_t stream) {
  const float* melspec = (const float*)d_in[0];
  const float* spec_init = (const float*)d_in[1];
  const float* fb = (const float*)d_in[2];
  float* out = (float*)d_out;

  int* m0f = (int*)d_ws;                          // 1025 ints
  float* w0a = (float*)((char*)d_ws + 5120);      // 1025 floats
  float* w1a = (float*)((char*)d_ws + 10240);     // 1025 floats

  imel_prep<<<dim3((N_STFT + 255) / 256), dim3(256), 0, stream>>>(fb, m0f, w0a, w1a);
  imel_main<<<dim3(1024), dim3(256), 0, stream>>>(melspec, spec_init, m0f, w0a, w1a, out);
}

// Round 2
// 150.600 us; speedup vs baseline: 6.3926x; 6.3926x over previous
//
#include <hip/hip_runtime.h>

#define N_STFT 1025
#define N_MELS 128
#define BATCH 4
#define TIME 1024
#define MAX_ITER 20

// Extract per-frequency sparse filterbank structure: each fb row f has at most
// 2 nonzeros at adjacent mel indices (m0, m0+1) — triangular filters.
__global__ void imel_prep(const float* __restrict__ fb, int* __restrict__ m0f,
                          float* __restrict__ w0a, float* __restrict__ w1a) {
  int f = blockIdx.x * blockDim.x + threadIdx.x;
  if (f >= N_STFT) return;
  const float* row = fb + (size_t)f * N_MELS;
  int m0 = -1;
  for (int m = 0; m < N_MELS; ++m) {
    if (row[m] != 0.0f) { m0 = m; break; }
  }
  if (m0 < 0) m0 = 0;                      // all-zero row (f=0): weights 0
  if (m0 > N_MELS - 2) m0 = N_MELS - 2;    // keep m0+1 in range
  m0f[f] = m0;
  w0a[f] = row[m0];
  w1a[f] = row[m0 + 1];
}

// One wave per (b,t) row; 4 waves (4 consecutive t) per workgroup.
// spec/buf/weights in registers; per-wave s_Pi (fixed-point) / s_diff in LDS.
// Forward scatter uses i32 fixed-point atomics: atomicAdd(int*) lowers to
// native no-return ds_add_u32 (fp32 atomicAdd risks a CAS-loop lowering,
// which is the round-1 887us pathology). Scale 2^24: P <= ~33 -> 5.5e8 < 2^31.
__global__ __launch_bounds__(256, 4) void imel_main(
    const float* __restrict__ melspec, const float* __restrict__ spec_init,
    const int* __restrict__ m0f, const float* __restrict__ w0a,
    const float* __restrict__ w1a, float* __restrict__ out) {
  __shared__ int   s_Pi[4][N_MELS];
  __shared__ float s_diff[4][N_MELS];
  __shared__ float s_out[4][1060];   // swizzle-padded: idx = f + (f>>5), max 1056

  const int tid = threadIdx.x;
  const int w = tid >> 6;       // wave = local row
  const int l = tid & 63;
  const int blk = blockIdx.x;
  const int b = blk >> 8;
  const int t0 = (blk & 255) << 2;
  const int t = t0 + w;

  const float SCALE = 16777216.0f;          // 2^24
  const float INV_SCALE = 1.0f / 16777216.0f;

  // lane owns contiguous chunk f in [16*l, 16*l+16); lane 63 also owns f=1024
  float rs[17], rb[17], rw0[17], rw1[17];   // rw0/rw1 pre-scaled by 2^24
  int rm0[17];

  const float* srow = spec_init + ((size_t)(b * TIME + t)) * N_STFT;
#pragma unroll
  for (int k = 0; k < 17; ++k) {
    const int f = (l << 4) + k;
    const bool ok = (k < 16) || (l == 63);
    if (ok) {
      rs[k] = srow[f];
      rm0[k] = m0f[f];
      rw0[k] = w0a[f] * SCALE;
      rw1[k] = w1a[f] * SCALE;
    } else {
      rs[k] = 0.f; rm0[k] = 0; rw0[k] = 0.f; rw1[k] = 0.f;
    }
    rb[k] = 0.f;
  }

  // mel targets for the diff phase: lane handles mels l and l+64
  const float melA = melspec[((size_t)b * N_MELS + l) * TIME + t];
  const float melB = melspec[((size_t)b * N_MELS + l + 64) * TIME + t];

  s_Pi[w][l] = 0;
  s_Pi[w][l + 64] = 0;
  __syncthreads();

  // grad prefactor (negated), with the 2^-24 fixed-point unscale folded in
  const float NEG_INV = -2.0f / (BATCH * TIME);
  const float NEG_INV_S = NEG_INV * INV_SCALE * INV_SCALE * SCALE;  // = NEG_INV*INV_SCALE... see below
  // rw* are scaled by 2^24; diff is unscaled; grad term d*rw -> needs *INV_SCALE once.
  const float GRAD_C = NEG_INV * INV_SCALE;

  for (int it = 0; it < MAX_ITER; ++it) {
    // ---- forward: P[m] += spec[f] * fb[f,m], 2-term i32 scatter per f ----
#pragma unroll
    for (int k = 0; k < 17; ++k) {
      if (k < 16 || l == 63) {
        atomicAdd(&s_Pi[w][rm0[k]],     __float2int_rn(rs[k] * rw0[k]));
        atomicAdd(&s_Pi[w][rm0[k] + 1], __float2int_rn(rs[k] * rw1[k]));
      }
    }
    __syncthreads();
    // ---- diff = mel - P; reset P for next iteration ----
    s_diff[w][l]      = melA - (float)s_Pi[w][l]      * INV_SCALE;
    s_diff[w][l + 64] = melB - (float)s_Pi[w][l + 64] * INV_SCALE;
    s_Pi[w][l] = 0;
    s_Pi[w][l + 64] = 0;
    __syncthreads();
    // ---- backward + momentum update + clamp ----
#pragma unroll
    for (int k = 0; k < 17; ++k) {
      if (k < 16 || l == 63) {
        const float d0 = s_diff[w][rm0[k]];
        const float d1 = s_diff[w][rm0[k] + 1];
        const float g = GRAD_C * (d0 * rw0[k] + d1 * rw1[k]);
        rb[k] = 0.9f * rb[k] + g;
        const float s = rs[k] - 0.3f * rb[k];
        rs[k] = s > 0.f ? s : 0.f;
      }
    }
    // barriers above order scatter->diff->backward; s_Pi/s_diff are wave-private
  }
  (void)NEG_INV_S;

  // ---- epilogue: transpose (row-major in regs) -> (B, F, T) via LDS ----
#pragma unroll
  for (int k = 0; k < 17; ++k) {
    if (k < 16 || l == 63) {
      const int f = (l << 4) + k;
      s_out[w][f + (f >> 5)] = rs[k];
    }
  }
  __syncthreads();

  const int tl = tid & 3;   // t offset within the WG's 4 rows
  const int fg = tid >> 2;  // 64 f phases
  float* obase = out + ((size_t)b * N_STFT) * TIME + t0 + tl;
  for (int f = fg; f < N_STFT; f += 64) {
    obase[(size_t)f * TIME] = s_out[tl][f + (f >> 5)];
  }
}

extern "C" void kernel_launch(void* const* d_in, const int* in_sizes, int n_in,
                              void* d_out, int out_size, void* d_ws, size_t ws_size,
                              hipStream_t stream) {
  const float* melspec = (const float*)d_in[0];
  const float* spec_init = (const float*)d_in[1];
  const float* fb = (const float*)d_in[2];
  float* out = (float*)d_out;

  int* m0f = (int*)d_ws;                          // 1025 ints
  float* w0a = (float*)((char*)d_ws + 5120);      // 1025 floats
  float* w1a = (float*)((char*)d_ws + 10240);     // 1025 floats

  imel_prep<<<dim3((N_STFT + 255) / 256), dim3(256), 0, stream>>>(fb, m0f, w0a, w1a);
  imel_main<<<dim3(1024), dim3(256), 0, stream>>>(melspec, spec_init, m0f, w0a, w1a, out);
}

// Round 3
// 134.431 us; speedup vs baseline: 7.1614x; 1.1203x over previous
//
#include <hip/hip_runtime.h>

#define N_STFT 1025
#define N_MELS 128
#define BATCH 4
#define TIME 1024
#define MAX_ITER 20

// Extract per-frequency sparse filterbank structure: each fb row f has at most
// 2 nonzeros at adjacent mel indices (m0, m0+1) — triangular filters.
// One wave per f row; ballot-scan replaces the serial 128-iteration loop.
__global__ void imel_prep(const float* __restrict__ fb, int* __restrict__ m0f,
                          float* __restrict__ w0a, float* __restrict__ w1a) {
  const int w = threadIdx.x >> 6, l = threadIdx.x & 63;
  const int f = blockIdx.x * 4 + w;
  if (f >= N_STFT) return;
  const float* row = fb + (size_t)f * N_MELS;
  const unsigned long long mlo = __ballot(row[l] != 0.0f);
  const unsigned long long mhi = __ballot(row[l + 64] != 0.0f);
  if (l == 0) {
    int m0 = mlo ? __builtin_ctzll(mlo)
                 : (mhi ? 64 + __builtin_ctzll(mhi) : 0);
    if (m0 > N_MELS - 2) m0 = N_MELS - 2;   // all-zero rows (f=0, f=1024) -> w=0
    m0f[f] = m0;
    w0a[f] = row[m0];
    w1a[f] = row[m0 + 1];
  }
}

// 512-thread blocks (8 waves) handle 4 rows; each row is split across 2 waves
// (each wave owns 512 freqs, lane chunk = 8 contiguous freqs). Grid = 1024
// blocks -> 4 blocks/CU x 8 waves = 32 waves/CU (full occupancy; needs VGPR<=64).
// Forward scatter: i32 fixed-point ds_add into 4 bank-skewed P replicas
// (replica = lane&3, row stride 129 -> bank (m0 + replica) % 32): kills the
// ~5 cyc/atomic bank serialization measured in round 2 (13.6M conflict cycles).
__global__ __launch_bounds__(512, 8) void imel_main(
    const float* __restrict__ melspec, const float* __restrict__ spec_init,
    const int* __restrict__ m0f, const float* __restrict__ w0a,
    const float* __restrict__ w1a, float* __restrict__ out) {
  __shared__ int   s_Pi[4][4][129];   // [row][replica][mel], skewed stride
  __shared__ float s_diff[4][N_MELS];
  __shared__ float s_out[4][1060];    // swizzle-padded: idx = f + (f>>5), max 1056

  const int tid = threadIdx.x;
  const int w   = tid >> 6;        // wave 0..7
  const int l   = tid & 63;
  const int row = w >> 1;          // local row 0..3
  const int h   = w & 1;           // which half of the freq axis
  const int c   = h * 64 + l;      // chunk index 0..127 (8 freqs each)
  const int r   = l & 3;           // P replica
  const int blk = blockIdx.x;
  const int b   = blk >> 8;
  const int t0  = (blk & 255) << 2;
  const int t   = t0 + row;

  const float SCALE = 16777216.0f;           // 2^24 fixed point
  const float INV_SCALE = 1.0f / 16777216.0f;

  // lane owns contiguous chunk f in [8c, 8c+8); chunk 127 also owns f=1024
  float rs[9], rb[9], rw0[9], rw1[9];        // rw* pre-scaled by 2^24
  int rm0[9];

  const float* srow = spec_init + (size_t)(b * TIME + t) * N_STFT;
#pragma unroll
  for (int k = 0; k < 9; ++k) {
    const int f = (c << 3) + k;
    const bool ok = (k < 8) || (c == 127);
    if (ok) {
      rs[k] = srow[f];
      rm0[k] = m0f[f];
      rw0[k] = w0a[f] * SCALE;
      rw1[k] = w1a[f] * SCALE;
    } else {
      rs[k] = 0.f; rm0[k] = 0; rw0[k] = 0.f; rw1[k] = 0.f;
    }
    rb[k] = 0.f;
  }

  // diff-phase role: thread -> (row dr, mel dm); load its mel target once
  const int dr = tid >> 7, dm = tid & 127;
  const float melD = melspec[((size_t)b * N_MELS + dm) * TIME + t0 + dr];

  // zero-init P replicas
  for (int i = tid; i < 4 * 4 * 129; i += 512) ((int*)s_Pi)[i] = 0;
  __syncthreads();

  // grad prefactor (negated) with one 2^-24 unscale folded in (rw* carry 2^24)
  const float GRAD_C = (-2.0f / (BATCH * TIME)) * INV_SCALE;

  for (int it = 0; it < MAX_ITER; ++it) {
    // ---- forward: P[m] += spec[f]*fb[f,m], 2-term i32 scatter per f ----
#pragma unroll
    for (int k = 0; k < 9; ++k) {
      if (k < 8 || c == 127) {
        atomicAdd(&s_Pi[row][r][rm0[k]],     __float2int_rn(rs[k] * rw0[k]));
        atomicAdd(&s_Pi[row][r][rm0[k] + 1], __float2int_rn(rs[k] * rw1[k]));
      }
    }
    __syncthreads();
    // ---- diff = mel - sum(replicas); reset replicas for next iter ----
    {
      const int p = s_Pi[dr][0][dm] + s_Pi[dr][1][dm] +
                    s_Pi[dr][2][dm] + s_Pi[dr][3][dm];
      s_diff[dr][dm] = melD - (float)p * INV_SCALE;
      s_Pi[dr][0][dm] = 0; s_Pi[dr][1][dm] = 0;
      s_Pi[dr][2][dm] = 0; s_Pi[dr][3][dm] = 0;
    }
    __syncthreads();
    // ---- backward gather + momentum update + clamp ----
#pragma unroll
    for (int k = 0; k < 9; ++k) {
      if (k < 8 || c == 127) {
        const float d0 = s_diff[row][rm0[k]];
        const float d1 = s_diff[row][rm0[k] + 1];
        const float g = GRAD_C * (d0 * rw0[k] + d1 * rw1[k]);
        rb[k] = 0.9f * rb[k] + g;
        const float s = rs[k] - 0.3f * rb[k];
        rs[k] = s > 0.f ? s : 0.f;
      }
    }
    // next scatter hits s_Pi (already reset + synced); s_diff rewrite is
    // gated by the scatter-phase __syncthreads -> no extra barrier needed
  }

  // ---- epilogue: transpose (f-major regs) -> (B, F, T) via swizzled LDS ----
#pragma unroll
  for (int k = 0; k < 9; ++k) {
    if (k < 8 || c == 127) {
      const int f = (c << 3) + k;
      s_out[row][f + (f >> 5)] = rs[k];
    }
  }
  __syncthreads();

  const int tl = tid & 3;    // t offset within the block's 4 rows
  const int fg = tid >> 2;   // 128 f phases
  float* obase = out + (size_t)b * N_STFT * TIME + t0 + tl;
  for (int f = fg; f < N_STFT; f += 128) {
    obase[(size_t)f * TIME] = s_out[tl][f + (f >> 5)];
  }
}

extern "C" void kernel_launch(void* const* d_in, const int* in_sizes, int n_in,
                              void* d_out, int out_size, void* d_ws, size_t ws_size,
                              hipStream_t stream) {
  const float* melspec = (const float*)d_in[0];
  const float* spec_init = (const float*)d_in[1];
  const float* fb = (const float*)d_in[2];
  float* out = (float*)d_out;

  int* m0f = (int*)d_ws;                          // 1025 ints
  float* w0a = (float*)((char*)d_ws + 5120);      // 1025 floats
  float* w1a = (float*)((char*)d_ws + 10240);     // 1025 floats

  imel_prep<<<dim3(257), dim3(256), 0, stream>>>(fb, m0f, w0a, w1a);
  imel_main<<<dim3(1024), dim3(512), 0, stream>>>(melspec, spec_init, m0f, w0a, w1a, out);
}